// Round 12
// baseline (88.169 us; speedup 1.0000x reference)
//
#include <hip/hip_runtime.h>
#include <math.h>
#include <utility>

#define TLEN 4096
#define NW   12
#define BLOCK 256
#define EPSF 1e-6f

typedef float v2f __attribute__((ext_vector_type(2)));

// Centered log10(w+1e-6) values (sum = 0) and 1/n_segments, precomputed in double.
__device__ const float XC_TAB[NW] = {
    -1.3608041f, -1.1303552f, -0.8694424f, -0.6126161f,
    -0.3608041f, -0.1128308f,  0.1388830f,  0.3889322f,
     0.6391959f,  0.8891277f,  1.1391578f,  1.2515558f };
__device__ const float INVN_TAB[NW] = {
    1.0f/409.0f, 1.0f/240.0f, 1.0f/132.0f, 1.0f/73.0f,
    1.0f/40.0f,  1.0f/23.0f,  1.0f/12.0f,  1.0f/7.0f,
    0.25f, 0.5f, 1.0f, 1.0f };
#define INV_DEN 0.11577579f
#define LOG10_2 0.30102999566f

__device__ __forceinline__ float max3f(float a, float b, float c) {
    float r; asm("v_max3_f32 %0, %1, %2, %3" : "=v"(r) : "v"(a), "v"(b), "v"(c)); return r;
}
__device__ __forceinline__ float min3f(float a, float b, float c) {
    float r; asm("v_min3_f32 %0, %1, %2, %3" : "=v"(r) : "v"(a), "v"(b), "v"(c)); return r;
}
__device__ __forceinline__ v2f pk_fma(v2f a, v2f b, v2f c) {
    v2f d; asm("v_pk_fma_f32 %0, %1, %2, %3" : "=v"(d) : "v"(a), "v"(b), "v"(c)); return d;
}
__device__ __forceinline__ v2f pk_add(v2f a, v2f b) {
    v2f d; asm("v_pk_add_f32 %0, %1, %2" : "=v"(d) : "v"(a), "v"(b)); return d;
}

__device__ __forceinline__ float wave_reduce_sum(float v) {
    #pragma unroll
    for (int o = 32; o > 0; o >>= 1) v += __shfl_xor(v, o, 64);
    return v;
}
template<int G>
__device__ __forceinline__ float reduce_leaders(float v) {
    #pragma unroll
    for (int o = G; o < 64; o <<= 1) v += __shfl_xor(v, o, 64);
    return v;
}

// R/S for one segment; P4[e] = P[4e], prefix of squared adjacent diffs.
// FLO = b&3, FHI = (b+W-1)&3, both compile-time at every call site.
template<int FLO, int FHI>
__device__ __forceinline__ float seg_rs2(const float* __restrict__ row,
                                         const float* __restrict__ P4,
                                         int b, int W, float m, float invwm2,
                                         float mx, float mn) {
    float plo = P4[b >> 2];
    if constexpr (FLO > 0) {
        const int k0 = b - FLO;
        #pragma unroll
        for (int t = 0; t < FLO; ++t) {
            float d = row[k0 + t + 1] - row[k0 + t];
            plo = fmaf(d, d, plo);
        }
    }
    const int e = b + W - 1;
    float phi = P4[e >> 2];
    if constexpr (FHI > 0) {
        const int k0 = e - FHI;
        #pragma unroll
        for (int t = 0; t < FHI; ++t) {
            float d = row[k0 + t + 1] - row[k0 + t];
            phi = fmaf(d, d, phi);
        }
    }
    float ss  = phi - plo;
    float var = fmaf(-(float)(W - 1) * m, m, ss) * invwm2;
    float S   = __builtin_amdgcn_sqrtf(fmaxf(var, 0.0f));
    return (mx - mn) * __builtin_amdgcn_rcpf(S + EPSF);
}

// Fold slots LO..HI of chunk q (j of slot s = JB + s, compile-time) into mx/mn.
template<int LO, int HI, int JB>
__device__ __forceinline__ void chunk_fold(const float4 q, float nm, float& mx, float& mn) {
    if constexpr (LO <= HI) {
        constexpr int NV = HI - LO + 1;
        float v[NV];
        #pragma unroll
        for (int r = 0; r < NV; ++r)
            v[r] = fmaf((float)(JB + LO + r), nm, (&q.x)[LO + r]);
        if constexpr (NV == 1) { mx = fmaxf(mx, v[0]); mn = fminf(mn, v[0]); }
        else if constexpr (NV == 2) { mx = max3f(mx, v[0], v[1]); mn = min3f(mn, v[0], v[1]); }
        else if constexpr (NV == 3) { mx = fmaxf(mx, max3f(v[0], v[1], v[2]));
                                      mn = fminf(mn, min3f(v[0], v[1], v[2])); }
        else { mx = max3f(max3f(mx, v[0], v[1]), v[2], v[3]);
               mn = min3f(min3f(mn, v[0], v[1]), v[2], v[3]); }
    }
}

// ---- W=17 thread-per-segment, compile-time alignment A = (17*s)&3 ----
// All endpoints and prefix fixups come from the 5 preloaded chunks.
template<int A>
__device__ __forceinline__ float w17_seg(const float* __restrict__ row,
                                         const float* __restrict__ P4, int s) {
    const int b = 17 * s;                 // b & 3 == A
    const int h = b >> 2;
    const float4* p = (const float4*)(row + b - A);
    float4 q0 = p[0], q1 = p[1], q2 = p[2], q3 = p[3], q4 = p[4];
    const float a0  = (&q0.x)[A];         // row[b]
    const float a16 = (&q4.x)[A];         // row[b+16]
    const float m = (a16 - a0) * (1.0f / 16.0f), nm = -m;
    float mx = -INFINITY, mn = INFINITY;
    chunk_fold<A + 1, 3, -A>(q0, nm, mx, mn);
    chunk_fold<0, 3, 4 - A>(q1, nm, mx, mn);
    chunk_fold<0, 3, 8 - A>(q2, nm, mx, mn);
    chunk_fold<0, 3, 12 - A>(q3, nm, mx, mn);
    chunk_fold<0, A, 16 - A>(q4, nm, mx, mn);
    float plo = P4[h];
    float phi = P4[h + 4];
    #pragma unroll
    for (int t = 0; t < A; ++t) {
        float d0 = (&q0.x)[t + 1] - (&q0.x)[t];
        plo = fmaf(d0, d0, plo);
        float d1 = (&q4.x)[t + 1] - (&q4.x)[t];
        phi = fmaf(d1, d1, phi);
    }
    float ss = phi - plo;
    float var = fmaf(-16.0f * m, m, ss) * (1.0f / 15.0f);
    float S = __builtin_amdgcn_sqrtf(fmaxf(var, 0.0f));
    return (mx - mn) * __builtin_amdgcn_rcpf(S + EPSF);
}

// ---- W=31 thread-per-segment, compile-time alignment A = (31*s)&3 ----
// Explicit scalars only (no arrays) to avoid scratch demotion.
template<int A>
__device__ __forceinline__ float w31_seg(const float* __restrict__ row,
                                         const float* __restrict__ P4, int s) {
    const int b = 31 * s;                 // b & 3 == A
    const int h = b >> 2;
    const float4* p = (const float4*)(row + b - A);
    float4 q0 = p[0], q1 = p[1], q2 = p[2], q3 = p[3];
    float4 q4 = p[4], q5 = p[5], q6 = p[6], q7 = p[7];
    float4 q8 = {};
    float a30;
    if constexpr (A >= 2) { q8 = p[8]; a30 = (&q8.x)[A - 2]; }
    else                  { a30 = (&q7.x)[A + 2]; }
    const float a0 = (&q0.x)[A];
    const float m = (a30 - a0) * (1.0f / 30.0f), nm = -m;
    float mx = -INFINITY, mn = INFINITY;
    chunk_fold<A + 1, 3, -A>(q0, nm, mx, mn);
    chunk_fold<0, 3, 4 - A>(q1, nm, mx, mn);
    chunk_fold<0, 3, 8 - A>(q2, nm, mx, mn);
    chunk_fold<0, 3, 12 - A>(q3, nm, mx, mn);
    chunk_fold<0, 3, 16 - A>(q4, nm, mx, mn);
    chunk_fold<0, 3, 20 - A>(q5, nm, mx, mn);
    chunk_fold<0, 3, 24 - A>(q6, nm, mx, mn);
    chunk_fold<0, (A + 2 < 3 ? A + 2 : 3), 28 - A>(q7, nm, mx, mn);
    if constexpr (A >= 2)
        chunk_fold<0, A - 2, 32 - A>(q8, nm, mx, mn);
    float plo = P4[h];
    #pragma unroll
    for (int t = 0; t < A; ++t) {
        float d0 = (&q0.x)[t + 1] - (&q0.x)[t];
        plo = fmaf(d0, d0, plo);
    }
    constexpr int HOF = (A + 30) >> 2;    // 7,7,8,8
    float phi = P4[h + HOF];
    if constexpr (A == 0) {
        float d0 = q7.y - q7.x; phi = fmaf(d0, d0, phi);
        float d1 = q7.z - q7.y; phi = fmaf(d1, d1, phi);
    } else if constexpr (A == 1) {
        float d0 = q7.y - q7.x; phi = fmaf(d0, d0, phi);
        float d1 = q7.z - q7.y; phi = fmaf(d1, d1, phi);
        float d2 = q7.w - q7.z; phi = fmaf(d2, d2, phi);
    } else if constexpr (A == 3) {
        float d0 = q8.y - q8.x; phi = fmaf(d0, d0, phi);
    }
    float ss = phi - plo;
    float var = fmaf(-30.0f * m, m, ss) * (1.0f / 29.0f);
    float S = __builtin_amdgcn_sqrtf(fmaxf(var, 0.0f));
    return (mx - mn) * __builtin_amdgcn_rcpf(S + EPSF);
}

// ---- Packed strided single-segment bulk with batched loads ----
template<int W, int A, int G>
__device__ __forceinline__ void seg_strided_pk(const float* __restrict__ row, int b, int lane,
                                               float nm, float& mx, float& mn) {
    constexpr int NCH  = (A + W - 1) / 4 + 1;
    constexpr int HIL  = (A + W - 1) & 3;
    constexpr int MAIN_END = (HIL == 3) ? NCH : NCH - 1;
    constexpr int NFULL = MAIN_END - 1;
    constexpr int FULL  = NFULL / G;
    constexpr int REM   = NFULL % G;
    constexpr int NB    = FULL + (REM > 0 ? 1 : 0);
    const float4* p  = (const float4*)(row + (b - A));
    const float4* pl = p + (1 + lane);
    float4 qs[NB > 0 ? NB : 1];
    #pragma unroll
    for (int i = 0; i < FULL; ++i) qs[i] = pl[i * G];
    if constexpr (REM > 0) { if (lane < REM) qs[FULL] = pl[FULL * G]; }
    mx = -INFINITY; mn = INFINITY;
    v2f jc; jc.x = (float)(4 * (1 + lane) - A); jc.y = jc.x + 1.0f;
    const v2f nm2   = {nm, nm};
    const v2f nm2x2 = {nm + nm, nm + nm};
    const v2f step  = {(float)(4 * G), (float)(4 * G)};
    #pragma unroll
    for (int i = 0; i < FULL; ++i) {
        float4 q = qs[i];
        v2f q01 = {q.x, q.y}, q23 = {q.z, q.w};
        v2f t01 = pk_fma(jc, nm2, q01);
        v2f t23 = pk_fma(jc, nm2, pk_add(q23, nm2x2));
        mx = max3f(max3f(mx, t01.x, t01.y), t23.x, t23.y);
        mn = min3f(min3f(mn, t01.x, t01.y), t23.x, t23.y);
        jc = pk_add(jc, step);
    }
    if constexpr (REM > 0) {
        if (lane < REM) {
            float4 q = qs[FULL];
            v2f q01 = {q.x, q.y}, q23 = {q.z, q.w};
            v2f t01 = pk_fma(jc, nm2, q01);
            v2f t23 = pk_fma(jc, nm2, pk_add(q23, nm2x2));
            mx = max3f(max3f(mx, t01.x, t01.y), t23.x, t23.y);
            mn = min3f(min3f(mn, t01.x, t01.y), t23.x, t23.y);
        }
    }
    if constexpr (A < 3) {
        if (lane == 0) chunk_fold<A + 1, 3, -A>(p[0], nm, mx, mn);
    }
    if constexpr (HIL != 3) {
        if (lane == 1) chunk_fold<0, HIL, 4 * (NCH - 1) - A>(p[NCH - 1], nm, mx, mn);
    }
}

template<int W, int A, int G>
__device__ __forceinline__ float group_seg(const float* __restrict__ row,
                                           const float* __restrict__ P4,
                                           int s, int lane) {
    const int b = s * W;
    float a0 = row[b], a1 = row[b + W - 1];
    float m = (a1 - a0) * (1.0f / (float)(W - 1));
    float nm = -m;
    float mx, mn;
    seg_strided_pk<W, A, G>(row, b, lane, nm, mx, mn);
    #pragma unroll
    for (int o = G / 2; o > 0; o >>= 1) {
        mx = fmaxf(mx, __shfl_xor(mx, o, G));
        mn = fminf(mn, __shfl_xor(mn, o, G));
    }
    float r = seg_rs2<A, (A + W - 1) & 3>(
        row, P4, b, W, m, 1.0f / (float)(W - 2), mx, mn);
    return (lane == 0) ? r : 0.0f;
}

// One W=10 segment from a 10-value register array; ss = sum of its 9 squared diffs.
__device__ __forceinline__ float w10_seg10(const float (&v)[10], float ss) {
    const float m = (v[9] - v[0]) * (1.0f / 9.0f), nm = -m;
    float x1 = fmaf(1.0f, nm, v[1]);
    float x2 = fmaf(2.0f, nm, v[2]);
    float x3 = fmaf(3.0f, nm, v[3]);
    float x4 = fmaf(4.0f, nm, v[4]);
    float x5 = fmaf(5.0f, nm, v[5]);
    float x6 = fmaf(6.0f, nm, v[6]);
    float x7 = fmaf(7.0f, nm, v[7]);
    float x8 = fmaf(8.0f, nm, v[8]);
    float x9 = fmaf(9.0f, nm, v[9]);
    float mx = max3f(x1, x2, x3);
    mx = max3f(mx, x4, x5); mx = max3f(mx, x6, x7); mx = max3f(mx, x8, x9);
    float mn = min3f(x1, x2, x3);
    mn = min3f(mn, x4, x5); mn = min3f(mn, x6, x7); mn = min3f(mn, x8, x9);
    float var = fmaf(-9.0f * m, m, ss) * 0.125f;
    float S = __builtin_amdgcn_sqrtf(fmaxf(var, 0.0f));
    return (mx - mn) * __builtin_amdgcn_rcpf(S + EPSF);
}

__global__ __launch_bounds__(BLOCK, 7) void hurst_kernel(const float* __restrict__ x,
                                                         float* __restrict__ out) {
    __shared__ __align__(16) float row[TLEN];
    __shared__ __align__(16) float P4[TLEN / 4];
    __shared__ float rs_sum[NW];
    __shared__ float wred[8];
    __shared__ float wredB[24];

    const int tid = threadIdx.x;
    const int r = blockIdx.x;
    const int w = tid >> 6, l = tid & 63;

    // One coalesced HBM pass per row.
    const float4* src = (const float4*)(x + (size_t)r * TLEN);
    float4* dst = (float4*)row;
    #pragma unroll
    for (int i = 0; i < TLEN / 4 / BLOCK; ++i)
        dst[tid + i * BLOCK] = src[tid + i * BLOCK];
    if (tid < NW) rs_sum[tid] = 0.0f;
    __syncthreads();

    // ==== Phase B (merged, low-register): W=10 + P4 build. Thread t owns 20t..20t+19. ====
    {
        float lp1 = 0.0f, lp2 = 0.0f, lp3 = 0.0f, lp4 = 0.0f;  // P snapshots at j=4,8,12,16
        float total = 0.0f;
        float contrib = 0.0f;
        if (tid < 205) {
            const int b = tid * 20;
            const float4* p = (const float4*)(row + b);
            // ---- half 1: elements 0..11 (q0..q2) ----
            float4 q0 = p[0], q1 = p[1], q2 = p[2];
            float v[12] = {q0.x,q0.y,q0.z,q0.w, q1.x,q1.y,q1.z,q1.w,
                           q2.x,q2.y,q2.z,q2.w};
            float c = 0.0f, s9 = 0.0f;
            #pragma unroll
            for (int j = 0; j < 10; ++j) {
                if (j == 4) lp1 = c;
                if (j == 8) lp2 = c;
                if (j == 9) s9 = c;
                float d = v[j + 1] - v[j];
                c = fmaf(d, d, c);
            }
            {
                float a1[10] = {v[0],v[1],v[2],v[3],v[4],v[5],v[6],v[7],v[8],v[9]};
                contrib = w10_seg10(a1, s9);
            }
            const float s10 = c;                 // P[b+10]
            const float v10 = v[10], v11 = v[11];
            float d10 = v11 - v10;
            c = fmaf(d10, d10, c);               // P[b+11]
            if (tid < 204) {
                // ---- half 2: elements 12..20 (q3,q4 + first of next chunk) ----
                float4 q3 = p[3], q4 = p[4];
                float u[8] = {q3.x,q3.y,q3.z,q3.w, q4.x,q4.y,q4.z,q4.w};
                float vlast = row[b + 20];
                float d11 = u[0] - v11;
                c = fmaf(d11, d11, c);           // P[b+12]
                lp3 = c;
                float s19 = 0.0f;
                #pragma unroll
                for (int j = 12; j < 20; ++j) {
                    if (j == 16) lp4 = c;
                    if (j == 19) s19 = c;
                    float nxt = (j + 1 < 20) ? u[j - 11] : vlast;
                    float d = nxt - u[j - 12];
                    c = fmaf(d, d, c);
                }
                float a2[10] = {v10, v11, u[0],u[1],u[2],u[3],u[4],u[5],u[6],u[7]};
                contrib += w10_seg10(a2, s19 - s10);
                total = c;                       // P[b+20]
            } else {
                // tid == 204: elements 12..15 only (q3); diffs d11..d14.
                float4 q3 = p[3];
                float d11 = q3.x - v11;
                c = fmaf(d11, d11, c);
                lp3 = c;
                float d12 = q3.y - q3.x; c = fmaf(d12, d12, c);
                float d13 = q3.z - q3.y; c = fmaf(d13, d13, c);
                float d14 = q3.w - q3.z; c = fmaf(d14, d14, c);
                total = c;
            }
        }
        // Exclusive scan of totals across the block (20-float granularity).
        float incl = total;
        #pragma unroll
        for (int o = 1; o < 64; o <<= 1) {
            float u = __shfl_up(incl, o, 64);
            if (l >= o) incl += u;
        }
        if (l == 63) wred[w] = incl;
        // W=10 accumulate (independent of the scan).
        float a = wave_reduce_sum(contrib);
        if (l == 0) atomicAdd(&rs_sum[0], a);
        __syncthreads();
        float off = incl - total;
        #pragma unroll
        for (int w2 = 0; w2 < 4; ++w2)
            if (w2 < w) off += wred[w2];
        if (tid < 204) {
            const int h = tid * 5;
            P4[h]     = off;
            P4[h + 1] = off + lp1;
            P4[h + 2] = off + lp2;
            P4[h + 3] = off + lp3;
            P4[h + 4] = off + lp4;
        } else if (tid == 204) {
            P4[1020] = off;
            P4[1021] = off + lp1;
            P4[1022] = off + lp2;
            P4[1023] = off + lp3;
        }
        __syncthreads();
    }

    // ================= wave phase (no __syncthreads inside) =================

    // W=17 (idx 1): thread-per-seg, parity-classed. Wave w -> segs s = 4l + w (A = w).
    {
        float a = 0.0f;
        if (l < 60) {
            const int s = 4 * l + w;
            if (w == 0)      a = w17_seg<0>(row, P4, s);
            else if (w == 1) a = w17_seg<1>(row, P4, s);
            else if (w == 2) a = w17_seg<2>(row, P4, s);
            else             a = w17_seg<3>(row, P4, s);
        }
        a = wave_reduce_sum(a);
        if (l == 0) atomicAdd(&rs_sum[1], a);
    }
    // W=31 (idx 2): thread-per-seg, parity-classed. Wave w -> segs s = 4l + w.
    // A = (31*s)&3: s%4=0->0, 1->3, 2->2, 3->1.
    {
        float a = 0.0f;
        if (l < 33) {
            const int s = 4 * l + w;
            if (w == 0)      a = w31_seg<0>(row, P4, s);
            else if (w == 1) a = w31_seg<3>(row, P4, s);
            else if (w == 2) a = w31_seg<2>(row, P4, s);
            else             a = w31_seg<1>(row, P4, s);
        }
        a = wave_reduce_sum(a);
        if (l == 0) atomicAdd(&rs_sum[2], a);
    }
    // W=56 (idx 3) pass1: segs 0..63, G=4.
    {
        float a = group_seg<56, 0, 4>(row, P4, tid >> 2, tid & 3);
        a = reduce_leaders<4>(a);
        if (l == 0) atomicAdd(&rs_sum[3], a);
    }
    // W=100 (idx 4) pass1: segs 0..31, G=8.
    {
        float a = group_seg<100, 0, 8>(row, P4, tid >> 3, tid & 7);
        a = reduce_leaders<8>(a);
        if (l == 0) atomicAdd(&rs_sum[4], a);
    }
    // W=177 (idx 5): G=16; alignment class A = s&3 mapped per wave.
    {
        const int g4 = (tid >> 4) & 3, gl16 = tid & 15;
        float a = 0.0f;
        if (w == 0) {
            a = group_seg<177, 0, 16>(row, P4, 4 * g4, gl16);
            if (g4 < 2) a += group_seg<177, 0, 16>(row, P4, 4 * (g4 + 4), gl16);
        } else if (w == 1) {
            a = group_seg<177, 1, 16>(row, P4, 4 * g4 + 1, gl16);
            if (g4 < 2) a += group_seg<177, 1, 16>(row, P4, 4 * (g4 + 4) + 1, gl16);
        } else if (w == 2) {
            a = group_seg<177, 2, 16>(row, P4, 4 * g4 + 2, gl16);
            if (g4 < 2) a += group_seg<177, 2, 16>(row, P4, 4 * (g4 + 4) + 2, gl16);
        } else {
            a = group_seg<177, 3, 16>(row, P4, 4 * g4 + 3, gl16);
            if (g4 < 1) a += group_seg<177, 3, 16>(row, P4, 4 * (g4 + 4) + 3, gl16);
        }
        a = reduce_leaders<16>(a);
        if (l == 0) atomicAdd(&rs_sum[5], a);
    }

    // Per-wave extras (balanced):
    if (w == 0) {
        // W=100 pass2: segs 32..39, G=8.
        float c2 = group_seg<100, 0, 8>(row, P4, 32 + (l >> 3), l & 7);
        c2 = reduce_leaders<8>(c2);
        if (l == 0) atomicAdd(&rs_sum[4], c2);
        // W=316 (idx 6) segs 8..11.
        float c1 = group_seg<316, 0, 16>(row, P4, 8 + ((l >> 4) & 3), l & 15);
        c1 = reduce_leaders<16>(c1);
        if (l == 0) atomicAdd(&rs_sum[6], c1);
    } else if (w == 1) {
        // W=562 (idx 7) even segs {0,2} and {4,6}: A=0, G=32.
        float c1 = group_seg<562, 0, 32>(row, P4, 2 * (l >> 5), l & 31);
        c1 += group_seg<562, 0, 32>(row, P4, 4 + 2 * (l >> 5), l & 31);
        c1 = reduce_leaders<32>(c1);
        if (l == 0) atomicAdd(&rs_sum[7], c1);
        // W=316 segs 4..7.
        float c6 = group_seg<316, 0, 16>(row, P4, 4 + ((l >> 4) & 3), l & 15);
        c6 = reduce_leaders<16>(c6);
        if (l == 0) atomicAdd(&rs_sum[6], c6);
    } else if (w == 2) {
        // W=562 odd segs {1,3}: A=2, G=32; seg {5}: A=2 on lanes 0..31.
        float c4 = group_seg<562, 2, 32>(row, P4, 1 + 2 * (l >> 5), l & 31);
        float c5 = (l < 32) ? group_seg<562, 2, 32>(row, P4, 5, l & 31) : 0.0f;
        c4 += c5;
        c4 = reduce_leaders<32>(c4);
        if (l == 0) atomicAdd(&rs_sum[7], c4);
        // W=56 pass2: segs 64..72 (9), G=4.
        float c3 = ((l >> 2) < 9) ? group_seg<56, 0, 4>(row, P4, 64 + (l >> 2), l & 3) : 0.0f;
        c3 = reduce_leaders<4>(c3);
        if (l == 0) atomicAdd(&rs_sum[3], c3);
    } else {
        // W=1000 (idx 8) segs {0,1} and {2,3}: G=32.
        float c3 = group_seg<1000, 0, 32>(row, P4, l >> 5, l & 31);
        c3 += group_seg<1000, 0, 32>(row, P4, 2 + (l >> 5), l & 31);
        c3 = reduce_leaders<32>(c3);
        if (l == 0) atomicAdd(&rs_sum[8], c3);
        // W=316 segs 0..3.
        float c4 = group_seg<316, 0, 16>(row, P4, (l >> 4) & 3, l & 15);
        c4 = reduce_leaders<16>(c4);
        if (l == 0) atomicAdd(&rs_sum[6], c4);
    }

    // ================= fused block phase (one barrier) =================
    {
        const int half = tid >> 7, hl = tid & 127;
        const int b17 = half ? 1778 : 0;
        float m17 = (row[b17 + 1777] - row[b17]) * (1.0f / 1777.0f);
        float mx17, mn17;
        if (half == 0) seg_strided_pk<1778, 0, 128>(row, 0,    hl, -m17, mx17, mn17);
        else           seg_strided_pk<1778, 2, 128>(row, 1778, hl, -m17, mx17, mn17);

        float m31 = (row[3161] - row[0]) * (1.0f / 3161.0f);
        float mx31, mn31;
        seg_strided_pk<3162, 0, 256>(row, 0, tid, -m31, mx31, mn31);

        float m40 = (row[4095] - row[0]) * (1.0f / 4095.0f);
        float mx40, mn40;
        seg_strided_pk<4096, 0, 256>(row, 0, tid, -m40, mx40, mn40);

        // Interleaved wave reduces (3 independent chains -> ILP).
        #pragma unroll
        for (int o = 32; o > 0; o >>= 1) {
            mx17 = fmaxf(mx17, __shfl_xor(mx17, o, 64));
            mn17 = fminf(mn17, __shfl_xor(mn17, o, 64));
            mx31 = fmaxf(mx31, __shfl_xor(mx31, o, 64));
            mn31 = fminf(mn31, __shfl_xor(mn31, o, 64));
            mx40 = fmaxf(mx40, __shfl_xor(mx40, o, 64));
            mn40 = fminf(mn40, __shfl_xor(mn40, o, 64));
        }
        if (l == 0) {
            float* wb = wredB + w * 6;
            wb[0] = mx17; wb[1] = mn17;
            wb[2] = mx31; wb[3] = mn31;
            wb[4] = mx40; wb[5] = mn40;
        }
        __syncthreads();
        if (tid == 0) {
            float MX = fmaxf(wredB[0], wredB[6]);
            float MN = fminf(wredB[1], wredB[7]);
            atomicAdd(&rs_sum[9],
                      seg_rs2<0, 1>(row, P4, 0, 1778, m17, 1.0f / 1776.0f, MX, MN));
        } else if (tid == 128) {
            float MX = fmaxf(wredB[12], wredB[18]);
            float MN = fminf(wredB[13], wredB[19]);
            atomicAdd(&rs_sum[9],
                      seg_rs2<2, 3>(row, P4, 1778, 1778, m17, 1.0f / 1776.0f, MX, MN));
        } else if (tid == 64) {
            float MX = fmaxf(fmaxf(wredB[2], wredB[8]),  fmaxf(wredB[14], wredB[20]));
            float MN = fminf(fminf(wredB[3], wredB[9]),  fminf(wredB[15], wredB[21]));
            atomicAdd(&rs_sum[10],
                      seg_rs2<0, 1>(row, P4, 0, 3162, m31, 1.0f / 3160.0f, MX, MN));
        } else if (tid == 192) {
            float MX = fmaxf(fmaxf(wredB[4], wredB[10]), fmaxf(wredB[16], wredB[22]));
            float MN = fminf(fminf(wredB[5], wredB[11]), fminf(wredB[17], wredB[23]));
            atomicAdd(&rs_sum[11],
                      seg_rs2<0, 3>(row, P4, 0, 4096, m40, 1.0f / 4094.0f, MX, MN));
        }
        __syncthreads();
    }

    // ================= epilogue =================
    if (tid < 64) {
        float t = 0.0f;
        if (tid < NW) {
            float rs = fmaf(rs_sum[tid], INVN_TAB[tid], EPSF);
            t = __builtin_amdgcn_logf(rs) * (LOG10_2) * XC_TAB[tid];
        }
        t = wave_reduce_sum(t);
        if (tid == 0) {
            float h = t * INV_DEN;
            if (!isfinite(h)) h = 1.0f;
            out[r] = h;
        }
    }
}

extern "C" void kernel_launch(void* const* d_in, const int* in_sizes, int n_in,
                              void* d_out, int out_size, void* d_ws, size_t ws_size,
                              hipStream_t stream) {
    const float* x = (const float*)d_in[0];
    float* out = (float*)d_out;
    const int B = out_size;  // 8192 rows
    hipLaunchKernelGGL(hurst_kernel, dim3(B), dim3(BLOCK), 0, stream, x, out);
}

// Round 13
// 84.550 us; speedup vs baseline: 1.0428x; 1.0428x over previous
//
#include <hip/hip_runtime.h>
#include <math.h>
#include <utility>

#define TLEN 4096
#define NW   12
#define BLOCK 256
#define EPSF 1e-6f

typedef float v2f __attribute__((ext_vector_type(2)));

// Centered log10(w+1e-6) values (sum = 0) and 1/n_segments, precomputed in double.
__device__ const float XC_TAB[NW] = {
    -1.3608041f, -1.1303552f, -0.8694424f, -0.6126161f,
    -0.3608041f, -0.1128308f,  0.1388830f,  0.3889322f,
     0.6391959f,  0.8891277f,  1.1391578f,  1.2515558f };
__device__ const float INVN_TAB[NW] = {
    1.0f/409.0f, 1.0f/240.0f, 1.0f/132.0f, 1.0f/73.0f,
    1.0f/40.0f,  1.0f/23.0f,  1.0f/12.0f,  1.0f/7.0f,
    0.25f, 0.5f, 1.0f, 1.0f };
#define INV_DEN 0.11577579f
#define LOG10_2 0.30102999566f

__device__ __forceinline__ float max3f(float a, float b, float c) {
    float r; asm("v_max3_f32 %0, %1, %2, %3" : "=v"(r) : "v"(a), "v"(b), "v"(c)); return r;
}
__device__ __forceinline__ float min3f(float a, float b, float c) {
    float r; asm("v_min3_f32 %0, %1, %2, %3" : "=v"(r) : "v"(a), "v"(b), "v"(c)); return r;
}
__device__ __forceinline__ v2f pk_fma(v2f a, v2f b, v2f c) {
    v2f d; asm("v_pk_fma_f32 %0, %1, %2, %3" : "=v"(d) : "v"(a), "v"(b), "v"(c)); return d;
}
__device__ __forceinline__ v2f pk_add(v2f a, v2f b) {
    v2f d; asm("v_pk_add_f32 %0, %1, %2" : "=v"(d) : "v"(a), "v"(b)); return d;
}

__device__ __forceinline__ float wave_reduce_sum(float v) {
    #pragma unroll
    for (int o = 32; o > 0; o >>= 1) v += __shfl_xor(v, o, 64);
    return v;
}
template<int G>
__device__ __forceinline__ float reduce_leaders(float v) {
    #pragma unroll
    for (int o = G; o < 64; o <<= 1) v += __shfl_xor(v, o, 64);
    return v;
}

// R/S for one segment; P4[e] = P[4e], prefix of squared adjacent diffs.
// FLO = b&3, FHI = (b+W-1)&3, both compile-time at every call site.
template<int FLO, int FHI>
__device__ __forceinline__ float seg_rs2(const float* __restrict__ row,
                                         const float* __restrict__ P4,
                                         int b, int W, float m, float invwm2,
                                         float mx, float mn) {
    float plo = P4[b >> 2];
    if constexpr (FLO > 0) {
        const int k0 = b - FLO;
        #pragma unroll
        for (int t = 0; t < FLO; ++t) {
            float d = row[k0 + t + 1] - row[k0 + t];
            plo = fmaf(d, d, plo);
        }
    }
    const int e = b + W - 1;
    float phi = P4[e >> 2];
    if constexpr (FHI > 0) {
        const int k0 = e - FHI;
        #pragma unroll
        for (int t = 0; t < FHI; ++t) {
            float d = row[k0 + t + 1] - row[k0 + t];
            phi = fmaf(d, d, phi);
        }
    }
    float ss  = phi - plo;
    float var = fmaf(-(float)(W - 1) * m, m, ss) * invwm2;
    float S   = __builtin_amdgcn_sqrtf(fmaxf(var, 0.0f));
    return (mx - mn) * __builtin_amdgcn_rcpf(S + EPSF);
}

// Fold slots LO..HI of chunk q (j of slot s = JB + s, compile-time) into mx/mn.
template<int LO, int HI, int JB>
__device__ __forceinline__ void chunk_fold(const float4 q, float nm, float& mx, float& mn) {
    if constexpr (LO <= HI) {
        constexpr int NV = HI - LO + 1;
        float v[NV];
        #pragma unroll
        for (int r = 0; r < NV; ++r)
            v[r] = fmaf((float)(JB + LO + r), nm, (&q.x)[LO + r]);
        if constexpr (NV == 1) { mx = fmaxf(mx, v[0]); mn = fminf(mn, v[0]); }
        else if constexpr (NV == 2) { mx = max3f(mx, v[0], v[1]); mn = min3f(mn, v[0], v[1]); }
        else if constexpr (NV == 3) { mx = fmaxf(mx, max3f(v[0], v[1], v[2]));
                                      mn = fminf(mn, min3f(v[0], v[1], v[2])); }
        else { mx = max3f(max3f(mx, v[0], v[1]), v[2], v[3]);
               mn = min3f(min3f(mn, v[0], v[1]), v[2], v[3]); }
    }
}

// ---- Multi-segment aligned tasks (proven family: base 16B-aligned, BP=0) ----
template<int W, int NSEG, int C>
__device__ __forceinline__ void mchunk_step(const float4* __restrict__ p,
                                            const float (&nm)[NSEG],
                                            float (&mx)[NSEG], float (&mn)[NSEG]) {
    constexpr int E0 = 4 * C;
    constexpr int K0 = E0 / W;
    constexpr int SA = K0 * W;
    constexpr int LOA = (SA == E0) ? 1 : 0;
    constexpr int HIA_ = SA + W - 1 - E0;
    constexpr int HIA = HIA_ < 3 ? HIA_ : 3;
    float4 q = p[C];
    if constexpr (K0 < NSEG)
        chunk_fold<LOA, HIA, E0 - SA>(q, nm[K0], mx[K0], mn[K0]);
    constexpr bool HASB = (K0 + 1 < NSEG) && (SA + W + 1 - E0 <= 3);
    if constexpr (HASB) {
        constexpr int SB = SA + W;
        chunk_fold<SB + 1 - E0, 3, E0 - SB>(q, nm[K0 + 1], mx[K0 + 1], mn[K0 + 1]);
    }
}

template<int W, int NSEG, int... Cs>
__device__ __forceinline__ void mseg_all(const float4* __restrict__ p,
                                         const float (&nm)[NSEG],
                                         float (&mx)[NSEG], float (&mn)[NSEG],
                                         std::integer_sequence<int, Cs...>) {
    (mchunk_step<W, NSEG, Cs>(p, nm, mx, mn), ...);
}

template<int W, int NSEG, int... Ks>
__device__ __forceinline__ float mseg_rs_all(const float* __restrict__ row,
                                             const float* __restrict__ P4, int b,
                                             const float (&m)[NSEG],
                                             const float (&mx)[NSEG], const float (&mn)[NSEG],
                                             std::integer_sequence<int, Ks...>) {
    constexpr float invwm2 = 1.0f / (float)(W - 2);
    float acc = 0.0f;
    ((acc += seg_rs2<(W * Ks) & 3, (W * Ks + W - 1) & 3>(
          row, P4, b + Ks * W, W, m[Ks], invwm2, mx[Ks], mn[Ks])), ...);
    return acc;
}

// Odd W, b divisible by 4 -> per-seg prefix residues are compile-time.
template<int W, int NSEG>
__device__ __forceinline__ float mseg_task_odd(const float* __restrict__ row,
                                               const float* __restrict__ P4, int b) {
    constexpr int NCH = (W * NSEG + 3) / 4;
    const float4* p = (const float4*)(row + b);
    float nm[NSEG], m[NSEG], mx[NSEG], mn[NSEG];
    #pragma unroll
    for (int k = 0; k < NSEG; ++k) {
        float a0 = row[b + k * W];
        float a1 = row[b + k * W + W - 1];
        m[k] = (a1 - a0) * (1.0f / (float)(W - 1));
        nm[k] = -m[k];
        mx[k] = -INFINITY; mn[k] = INFINITY;
    }
    mseg_all<W, NSEG>(p, nm, mx, mn, std::make_integer_sequence<int, NCH>{});
    return mseg_rs_all<W, NSEG>(row, P4, b, m, mx, mn,
                                std::make_integer_sequence<int, NSEG>{});
}

// ---- Packed strided single-segment bulk with batched loads ----
template<int W, int A, int G>
__device__ __forceinline__ void seg_strided_pk(const float* __restrict__ row, int b, int lane,
                                               float nm, float& mx, float& mn) {
    constexpr int NCH  = (A + W - 1) / 4 + 1;
    constexpr int HIL  = (A + W - 1) & 3;
    constexpr int MAIN_END = (HIL == 3) ? NCH : NCH - 1;
    constexpr int NFULL = MAIN_END - 1;
    constexpr int FULL  = NFULL / G;
    constexpr int REM   = NFULL % G;
    constexpr int NB    = FULL + (REM > 0 ? 1 : 0);
    const float4* p  = (const float4*)(row + (b - A));
    const float4* pl = p + (1 + lane);
    float4 qs[NB > 0 ? NB : 1];
    #pragma unroll
    for (int i = 0; i < FULL; ++i) qs[i] = pl[i * G];
    if constexpr (REM > 0) { if (lane < REM) qs[FULL] = pl[FULL * G]; }
    mx = -INFINITY; mn = INFINITY;
    v2f jc; jc.x = (float)(4 * (1 + lane) - A); jc.y = jc.x + 1.0f;
    const v2f nm2   = {nm, nm};
    const v2f nm2x2 = {nm + nm, nm + nm};
    const v2f step  = {(float)(4 * G), (float)(4 * G)};
    #pragma unroll
    for (int i = 0; i < FULL; ++i) {
        float4 q = qs[i];
        v2f q01 = {q.x, q.y}, q23 = {q.z, q.w};
        v2f t01 = pk_fma(jc, nm2, q01);
        v2f t23 = pk_fma(jc, nm2, pk_add(q23, nm2x2));
        mx = max3f(max3f(mx, t01.x, t01.y), t23.x, t23.y);
        mn = min3f(min3f(mn, t01.x, t01.y), t23.x, t23.y);
        jc = pk_add(jc, step);
    }
    if constexpr (REM > 0) {
        if (lane < REM) {
            float4 q = qs[FULL];
            v2f q01 = {q.x, q.y}, q23 = {q.z, q.w};
            v2f t01 = pk_fma(jc, nm2, q01);
            v2f t23 = pk_fma(jc, nm2, pk_add(q23, nm2x2));
            mx = max3f(max3f(mx, t01.x, t01.y), t23.x, t23.y);
            mn = min3f(min3f(mn, t01.x, t01.y), t23.x, t23.y);
        }
    }
    if constexpr (A < 3) {
        if (lane == 0) chunk_fold<A + 1, 3, -A>(p[0], nm, mx, mn);
    }
    if constexpr (HIL != 3) {
        if (lane == 1) chunk_fold<0, HIL, 4 * (NCH - 1) - A>(p[NCH - 1], nm, mx, mn);
    }
}

template<int W, int A, int G>
__device__ __forceinline__ float group_seg(const float* __restrict__ row,
                                           const float* __restrict__ P4,
                                           int s, int lane) {
    const int b = s * W;
    float a0 = row[b], a1 = row[b + W - 1];
    float m = (a1 - a0) * (1.0f / (float)(W - 1));
    float nm = -m;
    float mx, mn;
    seg_strided_pk<W, A, G>(row, b, lane, nm, mx, mn);
    #pragma unroll
    for (int o = G / 2; o > 0; o >>= 1) {
        mx = fmaxf(mx, __shfl_xor(mx, o, G));
        mn = fminf(mn, __shfl_xor(mn, o, G));
    }
    float r = seg_rs2<A, (A + W - 1) & 3>(
        row, P4, b, W, m, 1.0f / (float)(W - 2), mx, mn);
    return (lane == 0) ? r : 0.0f;
}

// One W=10 segment from a 10-value register array; ss = sum of its 9 squared diffs.
__device__ __forceinline__ float w10_seg10(const float (&v)[10], float ss) {
    const float m = (v[9] - v[0]) * (1.0f / 9.0f), nm = -m;
    float x1 = fmaf(1.0f, nm, v[1]);
    float x2 = fmaf(2.0f, nm, v[2]);
    float x3 = fmaf(3.0f, nm, v[3]);
    float x4 = fmaf(4.0f, nm, v[4]);
    float x5 = fmaf(5.0f, nm, v[5]);
    float x6 = fmaf(6.0f, nm, v[6]);
    float x7 = fmaf(7.0f, nm, v[7]);
    float x8 = fmaf(8.0f, nm, v[8]);
    float x9 = fmaf(9.0f, nm, v[9]);
    float mx = max3f(x1, x2, x3);
    mx = max3f(mx, x4, x5); mx = max3f(mx, x6, x7); mx = max3f(mx, x8, x9);
    float mn = min3f(x1, x2, x3);
    mn = min3f(mn, x4, x5); mn = min3f(mn, x6, x7); mn = min3f(mn, x8, x9);
    float var = fmaf(-9.0f * m, m, ss) * 0.125f;
    float S = __builtin_amdgcn_sqrtf(fmaxf(var, 0.0f));
    return (mx - mn) * __builtin_amdgcn_rcpf(S + EPSF);
}

__global__ __launch_bounds__(BLOCK, 7) void hurst_kernel(const float* __restrict__ x,
                                                         float* __restrict__ out) {
    __shared__ __align__(16) float row[TLEN];
    __shared__ __align__(16) float P4[TLEN / 4];
    __shared__ float rs_sum[NW];
    __shared__ float wred[8];
    __shared__ float wredB[24];

    const int tid = threadIdx.x;
    const int r = blockIdx.x;
    const int w = tid >> 6, l = tid & 63;

    // One coalesced HBM pass per row.
    const float4* src = (const float4*)(x + (size_t)r * TLEN);
    float4* dst = (float4*)row;
    #pragma unroll
    for (int i = 0; i < TLEN / 4 / BLOCK; ++i)
        dst[tid + i * BLOCK] = src[tid + i * BLOCK];
    if (tid < NW) rs_sum[tid] = 0.0f;
    __syncthreads();

    // ==== Phase B (merged, low-register): W=10 + P4 build. Thread t owns 20t..20t+19. ====
    {
        float lp1 = 0.0f, lp2 = 0.0f, lp3 = 0.0f, lp4 = 0.0f;  // P snapshots at j=4,8,12,16
        float total = 0.0f;
        float contrib = 0.0f;
        if (tid < 205) {
            const int b = tid * 20;
            const float4* p = (const float4*)(row + b);
            // ---- half 1: elements 0..11 (q0..q2) ----
            float4 q0 = p[0], q1 = p[1], q2 = p[2];
            float v[12] = {q0.x,q0.y,q0.z,q0.w, q1.x,q1.y,q1.z,q1.w,
                           q2.x,q2.y,q2.z,q2.w};
            float c = 0.0f, s9 = 0.0f;
            #pragma unroll
            for (int j = 0; j < 10; ++j) {
                if (j == 4) lp1 = c;
                if (j == 8) lp2 = c;
                if (j == 9) s9 = c;
                float d = v[j + 1] - v[j];
                c = fmaf(d, d, c);
            }
            {
                float a1[10] = {v[0],v[1],v[2],v[3],v[4],v[5],v[6],v[7],v[8],v[9]};
                contrib = w10_seg10(a1, s9);
            }
            const float s10 = c;                 // P[b+10]
            const float v10 = v[10], v11 = v[11];
            float d10 = v11 - v10;
            c = fmaf(d10, d10, c);               // P[b+11]
            if (tid < 204) {
                // ---- half 2: elements 12..20 (q3,q4 + first of next chunk) ----
                float4 q3 = p[3], q4 = p[4];
                float u[8] = {q3.x,q3.y,q3.z,q3.w, q4.x,q4.y,q4.z,q4.w};
                float vlast = row[b + 20];
                float d11 = u[0] - v11;
                c = fmaf(d11, d11, c);           // P[b+12]
                lp3 = c;
                float s19 = 0.0f;
                #pragma unroll
                for (int j = 12; j < 20; ++j) {
                    if (j == 16) lp4 = c;
                    if (j == 19) s19 = c;
                    float nxt = (j + 1 < 20) ? u[j - 11] : vlast;
                    float d = nxt - u[j - 12];
                    c = fmaf(d, d, c);
                }
                float a2[10] = {v10, v11, u[0],u[1],u[2],u[3],u[4],u[5],u[6],u[7]};
                contrib += w10_seg10(a2, s19 - s10);
                total = c;                       // P[b+20]
            } else {
                // tid == 204: elements 12..15 only (q3); diffs d11..d14.
                float4 q3 = p[3];
                float d11 = q3.x - v11;
                c = fmaf(d11, d11, c);
                lp3 = c;
                float d12 = q3.y - q3.x; c = fmaf(d12, d12, c);
                float d13 = q3.z - q3.y; c = fmaf(d13, d13, c);
                float d14 = q3.w - q3.z; c = fmaf(d14, d14, c);
                total = c;
            }
        }
        // Exclusive scan of totals across the block (20-float granularity).
        float incl = total;
        #pragma unroll
        for (int o = 1; o < 64; o <<= 1) {
            float u = __shfl_up(incl, o, 64);
            if (l >= o) incl += u;
        }
        if (l == 63) wred[w] = incl;
        // W=10 accumulate (independent of the scan).
        float a = wave_reduce_sum(contrib);
        if (l == 0) atomicAdd(&rs_sum[0], a);
        __syncthreads();
        float off = incl - total;
        #pragma unroll
        for (int w2 = 0; w2 < 4; ++w2)
            if (w2 < w) off += wred[w2];
        if (tid < 204) {
            const int h = tid * 5;
            P4[h]     = off;
            P4[h + 1] = off + lp1;
            P4[h + 2] = off + lp2;
            P4[h + 3] = off + lp3;
            P4[h + 4] = off + lp4;
        } else if (tid == 204) {
            P4[1020] = off;
            P4[1021] = off + lp1;
            P4[1022] = off + lp2;
            P4[1023] = off + lp3;
        }
        __syncthreads();
    }

    // ================= wave phase (no __syncthreads inside) =================

    // All-wave passes:
    // W=56 (idx 3) pass1: segs 0..63, G=4.
    {
        float a = group_seg<56, 0, 4>(row, P4, tid >> 2, tid & 3);
        a = reduce_leaders<4>(a);
        if (l == 0) atomicAdd(&rs_sum[3], a);
    }
    // W=100 (idx 4) pass1: segs 0..31, G=8.
    {
        float a = group_seg<100, 0, 8>(row, P4, tid >> 3, tid & 7);
        a = reduce_leaders<8>(a);
        if (l == 0) atomicAdd(&rs_sum[4], a);
    }
    // W=177 (idx 5): G=16; alignment class A = s&3 mapped per wave.
    {
        const int g4 = (tid >> 4) & 3, gl16 = tid & 15;
        float a = 0.0f;
        if (w == 0) {
            a = group_seg<177, 0, 16>(row, P4, 4 * g4, gl16);
            if (g4 < 2) a += group_seg<177, 0, 16>(row, P4, 4 * (g4 + 4), gl16);
        } else if (w == 1) {
            a = group_seg<177, 1, 16>(row, P4, 4 * g4 + 1, gl16);
            if (g4 < 2) a += group_seg<177, 1, 16>(row, P4, 4 * (g4 + 4) + 1, gl16);
        } else if (w == 2) {
            a = group_seg<177, 2, 16>(row, P4, 4 * g4 + 2, gl16);
            if (g4 < 2) a += group_seg<177, 2, 16>(row, P4, 4 * (g4 + 4) + 2, gl16);
        } else {
            a = group_seg<177, 3, 16>(row, P4, 4 * g4 + 3, gl16);
            if (g4 < 1) a += group_seg<177, 3, 16>(row, P4, 4 * (g4 + 4) + 3, gl16);
        }
        a = reduce_leaders<16>(a);
        if (l == 0) atomicAdd(&rs_sum[5], a);
    }

    // Per-wave extras (R9-proven distribution; scratch-free building blocks only):
    if (w == 0) {
        // W=17 (idx 1): 60 4-seg tasks.
        float a = (l < 60) ? mseg_task_odd<17, 4>(row, P4, l * 68) : 0.0f;
        a = wave_reduce_sum(a);
        if (l == 0) atomicAdd(&rs_sum[1], a);
        // W=316 (idx 6) segs 8..11.
        float c1 = group_seg<316, 0, 16>(row, P4, 8 + ((l >> 4) & 3), l & 15);
        c1 = reduce_leaders<16>(c1);
        if (l == 0) atomicAdd(&rs_sum[6], c1);
    } else if (w == 1) {
        // W=31 (idx 2): 33 4-seg tasks.
        float a = (l < 33) ? mseg_task_odd<31, 4>(row, P4, l * 124) : 0.0f;
        a = wave_reduce_sum(a);
        if (l == 0) atomicAdd(&rs_sum[2], a);
    } else if (w == 2) {
        // W=100 pass2: segs 32..39, G=8.
        float c2 = group_seg<100, 0, 8>(row, P4, 32 + (l >> 3), l & 7);
        c2 = reduce_leaders<8>(c2);
        if (l == 0) atomicAdd(&rs_sum[4], c2);
        // W=56 pass2: segs 64..72 (9), G=4.
        float c3 = ((l >> 2) < 9) ? group_seg<56, 0, 4>(row, P4, 64 + (l >> 2), l & 3) : 0.0f;
        c3 = reduce_leaders<4>(c3);
        if (l == 0) atomicAdd(&rs_sum[3], c3);
        // W=562 (idx 7) odd segs {1,3}: A=2, G=32.
        float c4 = group_seg<562, 2, 32>(row, P4, 1 + 2 * (l >> 5), l & 31);
        c4 = reduce_leaders<32>(c4);
        if (l == 0) atomicAdd(&rs_sum[7], c4);
        // W=1000 (idx 8) segs {0,1}: G=32.
        float c5 = group_seg<1000, 0, 32>(row, P4, l >> 5, l & 31);
        c5 = reduce_leaders<32>(c5);
        if (l == 0) atomicAdd(&rs_sum[8], c5);
        // W=316 segs 4..7.
        float c6 = group_seg<316, 0, 16>(row, P4, 4 + ((l >> 4) & 3), l & 15);
        c6 = reduce_leaders<16>(c6);
        if (l == 0) atomicAdd(&rs_sum[6], c6);
    } else {
        // W=562 even segs {0,2} and {4,6}: A=0, G=32; seg {5}: A=2.
        float c1 = group_seg<562, 0, 32>(row, P4, 2 * (l >> 5), l & 31);
        c1 += group_seg<562, 0, 32>(row, P4, 4 + 2 * (l >> 5), l & 31);
        float c2 = (l < 32) ? group_seg<562, 2, 32>(row, P4, 5, l & 31) : 0.0f;
        c1 += c2;
        c1 = reduce_leaders<32>(c1);
        if (l == 0) atomicAdd(&rs_sum[7], c1);
        // W=1000 segs {2,3}: G=32.
        float c3 = group_seg<1000, 0, 32>(row, P4, 2 + (l >> 5), l & 31);
        c3 = reduce_leaders<32>(c3);
        if (l == 0) atomicAdd(&rs_sum[8], c3);
        // W=316 segs 0..3.
        float c4 = group_seg<316, 0, 16>(row, P4, (l >> 4) & 3, l & 15);
        c4 = reduce_leaders<16>(c4);
        if (l == 0) atomicAdd(&rs_sum[6], c4);
    }

    // ================= fused block phase (one barrier) =================
    {
        const int half = tid >> 7, hl = tid & 127;
        const int b17 = half ? 1778 : 0;
        float m17 = (row[b17 + 1777] - row[b17]) * (1.0f / 1777.0f);
        float mx17, mn17;
        if (half == 0) seg_strided_pk<1778, 0, 128>(row, 0,    hl, -m17, mx17, mn17);
        else           seg_strided_pk<1778, 2, 128>(row, 1778, hl, -m17, mx17, mn17);

        float m31 = (row[3161] - row[0]) * (1.0f / 3161.0f);
        float mx31, mn31;
        seg_strided_pk<3162, 0, 256>(row, 0, tid, -m31, mx31, mn31);

        float m40 = (row[4095] - row[0]) * (1.0f / 4095.0f);
        float mx40, mn40;
        seg_strided_pk<4096, 0, 256>(row, 0, tid, -m40, mx40, mn40);

        // Interleaved wave reduces (3 independent chains -> ILP).
        #pragma unroll
        for (int o = 32; o > 0; o >>= 1) {
            mx17 = fmaxf(mx17, __shfl_xor(mx17, o, 64));
            mn17 = fminf(mn17, __shfl_xor(mn17, o, 64));
            mx31 = fmaxf(mx31, __shfl_xor(mx31, o, 64));
            mn31 = fminf(mn31, __shfl_xor(mn31, o, 64));
            mx40 = fmaxf(mx40, __shfl_xor(mx40, o, 64));
            mn40 = fminf(mn40, __shfl_xor(mn40, o, 64));
        }
        if (l == 0) {
            float* wb = wredB + w * 6;
            wb[0] = mx17; wb[1] = mn17;
            wb[2] = mx31; wb[3] = mn31;
            wb[4] = mx40; wb[5] = mn40;
        }
        __syncthreads();
        if (tid == 0) {
            float MX = fmaxf(wredB[0], wredB[6]);
            float MN = fminf(wredB[1], wredB[7]);
            atomicAdd(&rs_sum[9],
                      seg_rs2<0, 1>(row, P4, 0, 1778, m17, 1.0f / 1776.0f, MX, MN));
        } else if (tid == 128) {
            float MX = fmaxf(wredB[12], wredB[18]);
            float MN = fminf(wredB[13], wredB[19]);
            atomicAdd(&rs_sum[9],
                      seg_rs2<2, 3>(row, P4, 1778, 1778, m17, 1.0f / 1776.0f, MX, MN));
        } else if (tid == 64) {
            float MX = fmaxf(fmaxf(wredB[2], wredB[8]),  fmaxf(wredB[14], wredB[20]));
            float MN = fminf(fminf(wredB[3], wredB[9]),  fminf(wredB[15], wredB[21]));
            atomicAdd(&rs_sum[10],
                      seg_rs2<0, 1>(row, P4, 0, 3162, m31, 1.0f / 3160.0f, MX, MN));
        } else if (tid == 192) {
            float MX = fmaxf(fmaxf(wredB[4], wredB[10]), fmaxf(wredB[16], wredB[22]));
            float MN = fminf(fminf(wredB[5], wredB[11]), fminf(wredB[17], wredB[23]));
            atomicAdd(&rs_sum[11],
                      seg_rs2<0, 3>(row, P4, 0, 4096, m40, 1.0f / 4094.0f, MX, MN));
        }
        __syncthreads();
    }

    // ================= epilogue =================
    if (tid < 64) {
        float t = 0.0f;
        if (tid < NW) {
            float rs = fmaf(rs_sum[tid], INVN_TAB[tid], EPSF);
            t = __builtin_amdgcn_logf(rs) * (LOG10_2) * XC_TAB[tid];
        }
        t = wave_reduce_sum(t);
        if (tid == 0) {
            float h = t * INV_DEN;
            if (!isfinite(h)) h = 1.0f;
            out[r] = h;
        }
    }
}

extern "C" void kernel_launch(void* const* d_in, const int* in_sizes, int n_in,
                              void* d_out, int out_size, void* d_ws, size_t ws_size,
                              hipStream_t stream) {
    const float* x = (const float*)d_in[0];
    float* out = (float*)d_out;
    const int B = out_size;  // 8192 rows
    hipLaunchKernelGGL(hurst_kernel, dim3(B), dim3(BLOCK), 0, stream, x, out);
}